// Round 4
// baseline (342.650 us; speedup 1.0000x reference)
//
#include <hip/hip_runtime.h>

#define MROWS 400000
#define NOBS 1024

// ---------------------------------------------------------------------------
// Kernel A: per-row scoring MLP, writes e[row] = exp(score).
// Max-subtraction cancels algebraically in prob = e/sum(e); scores are O(1)
// so raw fp32 exp is safe (verified: absmax 4.9e-4 in R1-R3).
//
// R4: amdgpu_waves_per_eu(3,4) pins occupancy (R3's __launch_bounds__(256,3)
// only set a MINIMUM; compiler targeted 6 waves/EU, allocated 84 VGPR and
// spilled ~39 B/thread -> WRITE_SIZE 17 MB). With a pinned 3-4 waves/EU the
// 32-float4 full-row preload fits in registers: ~1.5-2 KB of loads in flight
// per SIMD (need ~2.3 KB for full HBM BW at ~900 cyc latency).
// ---------------------------------------------------------------------------
__global__ __attribute__((amdgpu_flat_work_group_size(256, 256),
                          amdgpu_waves_per_eu(3, 4)))
void score_kernel(
    const float* __restrict__ ht, const float* __restrict__ info,
    const float* __restrict__ w1, const float* __restrict__ b1,
    const float* __restrict__ w2, const float* __restrict__ b2,
    float* __restrict__ evec) {
    const int row = blockIdx.x * 256 + threadIdx.x;
    if (row >= MROWS) return;

    const float4* pa = (const float4*)(ht   + (size_t)row * 64);
    const float4* pb = (const float4*)(info + (size_t)row * 64);

    float4 xa[16], xb[16];
#pragma unroll
    for (int i = 0; i < 16; ++i) xa[i] = pa[i];
#pragma unroll
    for (int i = 0; i < 16; ++i) xb[i] = pb[i];

    float h[16];
#pragma unroll
    for (int j = 0; j < 16; ++j) h[j] = b1[j];

#pragma unroll
    for (int i = 0; i < 16; ++i) {
        const float4 v = xa[i];
        const float* wr = w1 + (4 * i) * 16;
#pragma unroll
        for (int j = 0; j < 16; ++j)
            h[j] += v.x * wr[j] + v.y * wr[16 + j] + v.z * wr[32 + j] + v.w * wr[48 + j];
    }
#pragma unroll
    for (int i = 0; i < 16; ++i) {
        const float4 v = xb[i];
        const float* wr = w1 + (64 + 4 * i) * 16;
#pragma unroll
        for (int j = 0; j < 16; ++j)
            h[j] += v.x * wr[j] + v.y * wr[16 + j] + v.z * wr[32 + j] + v.w * wr[48 + j];
    }

    float s = b2[0];
#pragma unroll
    for (int j = 0; j < 16; ++j) s += fmaxf(h[j], 0.0f) * w2[j];

    evec[row] = __expf(s);
}

// ---------------------------------------------------------------------------
// Kernel B: one block per segment (segments sorted -> contiguous row range via
// binary search). 384 threads = 6 waves = 2 row-teams x 3 feature arrays.
// Each wave covers 2 rows/iter with float2 lanes (512 B coalesced per instr),
// unroll 4 -> 8 independent loads in flight. shfl_xor(32) folds row parity,
// LDS folds the two teams. No atomics, no init kernels.
// (Unchanged in R4 so its true dur_us surfaces in top-5 once score drops.)
// ---------------------------------------------------------------------------
__global__ __launch_bounds__(384) void pool_kernel(
    const float* __restrict__ ht, const float* __restrict__ info,
    const float* __restrict__ fut, const int* __restrict__ seg,
    const float* __restrict__ evec, float* __restrict__ out) {
    const int s = blockIdx.x;

    int lo = 0, hi = MROWS;
    while (lo < hi) { int mid = (lo + hi) >> 1; if (seg[mid] < s) lo = mid + 1; else hi = mid; }
    const int start = lo;
    hi = MROWS;
    while (lo < hi) { int mid = (lo + hi) >> 1; if (seg[mid] < s + 1) lo = mid + 1; else hi = mid; }
    const int end = lo;

    const int t    = threadIdx.x;
    const int wave = t >> 6;          // 0..5
    const int lane = t & 63;
    const int arr  = wave >> 1;       // 0,1,2 -> ht, info, fut
    const int team = wave & 1;        // 0,1   -> row halves
    const float* base = (arr == 0) ? ht : (arr == 1) ? info : fut;  // wave-uniform
    const int ro = lane >> 5;         // row offset within pair: 0/1
    const int d2 = (lane & 31) * 2;   // dim pair

    const int mid = (start + end) >> 1;
    const int rbeg = team ? mid : start;
    const int rend = team ? end : mid;

    float accx = 0.f, accy = 0.f, ds = 0.f;
    int r = rbeg;
    for (; r + 8 <= rend; r += 8) {
        float2 x[4]; float ev[4];
#pragma unroll
        for (int u = 0; u < 4; ++u)
            x[u] = *(const float2*)(base + (size_t)(r + 2 * u + ro) * 64 + d2);
#pragma unroll
        for (int u = 0; u < 4; ++u) ev[u] = evec[r + 2 * u + ro];
#pragma unroll
        for (int u = 0; u < 4; ++u) {
            accx += ev[u] * x[u].x;
            accy += ev[u] * x[u].y;
            ds   += ev[u];
        }
    }
    for (; r < rend; r += 2) {
        const int rr = r + ro;
        if (rr < rend) {
            const float e = evec[rr];
            const float2 x = *(const float2*)(base + (size_t)rr * 64 + d2);
            accx += e * x.x;
            accy += e * x.y;
            ds   += e;
        }
    }

    // fold the two row-parity halves (lane l <-> l^32 hold the same dims)
    accx += __shfl_xor(accx, 32, 64);
    accy += __shfl_xor(accy, 32, 64);
    ds   += __shfl_xor(ds,   32, 64);

    // fold the two teams through LDS
    __shared__ float2 part[3][32];
    __shared__ float dpart;
    if (team == 1 && lane < 32) part[arr][lane] = make_float2(accx, accy);
    if (wave == 1 && lane == 0) dpart = ds;
    __syncthreads();

    if (team == 0 && lane < 32) {
        const float2 p = part[arr][lane];
        const float dt = ds + dpart;
        const float inv = 1.0f / dt;
        float2 o;
        o.x = (accx + p.x) * inv;
        o.y = (accy + p.y) * inv;
        *(float2*)(out + (size_t)s * 192 + arr * 64 + d2) = o;
    }
}

extern "C" void kernel_launch(void* const* d_in, const int* in_sizes, int n_in,
                              void* d_out, int out_size, void* d_ws, size_t ws_size,
                              hipStream_t stream) {
    const float* ht   = (const float*)d_in[0];
    const float* info = (const float*)d_in[1];
    const float* fut  = (const float*)d_in[2];
    const int*   seg  = (const int*)d_in[3];
    const float* w1   = (const float*)d_in[4];
    const float* b1   = (const float*)d_in[5];
    const float* w2   = (const float*)d_in[6];
    const float* b2   = (const float*)d_in[7];

    float* out  = (float*)d_out;
    float* evec = (float*)d_ws;   // M floats = 1.6 MB scratch

    score_kernel<<<(MROWS + 255) / 256, 256, 0, stream>>>(ht, info, w1, b1, w2, b2, evec);
    pool_kernel<<<NOBS, 384, 0, stream>>>(ht, info, fut, seg, evec, out);
}